// Round 11
// baseline (351.111 us; speedup 1.0000x reference)
//
#include <hip/hip_runtime.h>

typedef _Float16 half8 __attribute__((ext_vector_type(8)));
typedef _Float16 half4v __attribute__((ext_vector_type(4)));
typedef _Float16 half2v __attribute__((ext_vector_type(2)));
typedef float f32x4 __attribute__((ext_vector_type(4)));
typedef float f32x2 __attribute__((ext_vector_type(2)));

#define CAP 32          // bucket capacity per output point (mean load = 5)
#define OVF_MAX 4096

// Y is COMPACTED: only used (j,k) cells get a row, at index cidx[cell]
// (exclusive prefix sum of the byte mask). ~707K rows x 256B = 181 MB,
// Infinity-Cache-resident for gather's 1M random row reads.
// GEMM epilogue uses NONTEMPORAL stores (R11): L3 is memory-side so NT data
// still lands in L3 for gather, while avoiding the L2 write-allocate
// pollution that cost gemm +24us in R10 (write BW 2.38 -> 1.83 TB/s).
// Row-internal permutation: o = (o'>>6)*64 + (o'&3)*16 + ((o'>>2)&15)

// ---------------- out[i][o] = bias[o] (fallback path only) ------------------
__global__ void init_bias(float* __restrict__ out, const float* __restrict__ bias, int n4) {
    int i = blockIdx.x * blockDim.x + threadIdx.x;
    if (i >= n4) return;
    reinterpret_cast<float4*>(out)[i] = reinterpret_cast<const float4*>(bias)[i & 31];
}

// ---------------- fused: fp32->fp16 cvt + bias perm + Y zero row + mask -----
__global__ __launch_bounds__(256) void cvt_mask(
    const float* __restrict__ x, const float* __restrict__ w,
    const float* __restrict__ bias,
    _Float16* __restrict__ Xh, _Float16* __restrict__ Wh,
    float* __restrict__ biasPerm, _Float16* __restrict__ Yz,
    const int* __restrict__ jl, const int* __restrict__ kc,
    unsigned char* __restrict__ maskB,
    int Mpad, int xv4, int xt4, int w4, int E) {
    int i = blockIdx.x * blockDim.x + threadIdx.x;
    if (i < xt4) {
        float4 v = (i < xv4) ? reinterpret_cast<const float4*>(x)[i]
                             : make_float4(0.f, 0.f, 0.f, 0.f);
        half4v h; h[0]=(_Float16)v.x; h[1]=(_Float16)v.y; h[2]=(_Float16)v.z; h[3]=(_Float16)v.w;
        reinterpret_cast<half4v*>(Xh)[i] = h;
    } else if (i < xt4 + w4) {
        int j = i - xt4;
        float4 v = reinterpret_cast<const float4*>(w)[j];
        half4v h; h[0]=(_Float16)v.x; h[1]=(_Float16)v.y; h[2]=(_Float16)v.z; h[3]=(_Float16)v.w;
        reinterpret_cast<half4v*>(Wh)[j] = h;
    } else if (i < xt4 + w4 + 32) {
        int j2 = i - xt4 - w4;           // float4 index into biasPerm (o'=4*j2)
        int wn = j2 >> 4, mrow = j2 & 15;
        float4 v;
        v.x = bias[wn * 64 + 0 * 16 + mrow];
        v.y = bias[wn * 64 + 1 * 16 + mrow];
        v.z = bias[wn * 64 + 2 * 16 + mrow];
        v.w = bias[wn * 64 + 3 * 16 + mrow];
        reinterpret_cast<float4*>(biasPerm)[j2] = v;
    } else if (i < xt4 + w4 + 48) {
        int t = i - xt4 - w4 - 32;       // Y zero row: 16 x int4 = 256 B
        reinterpret_cast<int4*>(Yz)[t] = make_int4(0, 0, 0, 0);
    } else {
        int e = i - (xt4 + w4 + 48);
        if (e < E) maskB[(size_t)kc[e] * Mpad + jl[e]] = 1;  // idempotent store
    }
}

// ---------------- scan pass 1: per-block (4KB) mask sums --------------------
__global__ __launch_bounds__(256) void scan_sums(
    const unsigned* __restrict__ m4, int n4, int* __restrict__ bsums) {
    int base = blockIdx.x * 1024 + threadIdx.x * 4;
    int s = 0;
#pragma unroll
    for (int t = 0; t < 4; ++t) {
        int idx = base + t;
        if (idx < n4) s += __popc(m4[idx]);   // bytes are 0/1 -> popcount
    }
#pragma unroll
    for (int o = 32; o; o >>= 1) s += __shfl_xor(s, o);
    __shared__ int ws[4];
    if ((threadIdx.x & 63) == 0) ws[threadIdx.x >> 6] = s;
    __syncthreads();
    if (threadIdx.x == 0) bsums[blockIdx.x] = ws[0] + ws[1] + ws[2] + ws[3];
}

// ---------------- scan pass 2: write exclusive prefix (cidx per cell) -------
__global__ __launch_bounds__(256) void scan_write(
    const unsigned* __restrict__ m4, int n4,
    const int* __restrict__ bsums, int* __restrict__ cidx) {
    const int tid = threadIdx.x, b = blockIdx.x;
    int acc = 0;
    for (int i = tid; i < b; i += 256) acc += bsums[i];   // <=330 ints, trivial
#pragma unroll
    for (int o = 32; o; o >>= 1) acc += __shfl_xor(acc, o);
    __shared__ int ws[4];
    __shared__ int tsum[256];
    if ((tid & 63) == 0) ws[tid >> 6] = acc;
    __syncthreads();
    const int blockOff = ws[0] + ws[1] + ws[2] + ws[3];
    int base = b * 1024 + tid * 4;           // uint index (16 cells/thread)
    unsigned v[4]; int ts = 0;
#pragma unroll
    for (int t = 0; t < 4; ++t) {
        int idx = base + t;
        v[t] = (idx < n4) ? m4[idx] : 0u;
        ts += __popc(v[t]);
    }
    tsum[tid] = ts;
    __syncthreads();
    for (int o = 1; o < 256; o <<= 1) {      // Hillis-Steele inclusive scan
        int y = (tid >= o) ? tsum[tid - o] : 0;
        __syncthreads();
        tsum[tid] += y;
        __syncthreads();
    }
    int run = blockOff + tsum[tid] - ts;     // exclusive prefix for this thread
#pragma unroll
    for (int t = 0; t < 4; ++t) {
        int idx = base + t;
        if (idx < n4) {
            unsigned wv = v[t];
            int4 o4;
            o4.x = run; run += (wv & 1u);
            o4.y = run; run += ((wv >> 8) & 1u);
            o4.z = run; run += ((wv >> 16) & 1u);
            o4.w = run; run += ((wv >> 24) & 1u);
            reinterpret_cast<int4*>(cidx)[idx] = o4;
        }
    }
}

// ---------------- GEMM: Ycomp[cidx[k,m]] = X[m,:] * W[k]^T ------------------
// R9's verified BM=64 schedule (3 blocks/CU) + compacted epilogue (ballot +
// popcll row slots) + NONTEMPORAL stores (R11 revert of R10's regression).
__global__ __launch_bounds__(256, 3) void gemm_xw(
    const _Float16* __restrict__ Xh,   // [Mpad][128]
    const _Float16* __restrict__ Wh,   // [K][128][128]  (o-major, c contiguous)
    _Float16* __restrict__ Y,          // compacted [NC][128]
    const unsigned char* __restrict__ maskB, // used-cell bytes, idx = kcell*Mpad+m
    const int* __restrict__ cidx,      // exclusive prefix of maskB
    int Mpad, int KD,                  // KD = K/3 (y-blocks per m-tile)
    const int* __restrict__ ih, const int* __restrict__ jl,
    const int* __restrict__ kc,
    int* __restrict__ counts, int* __restrict__ bucket,
    int* __restrict__ ovf_cnt, int* __restrict__ ovf_list, int E) {
    __shared__ ushort sA[64 * 128];    // 16 KB
    __shared__ ushort sB[128 * 128];   // 32 KB
    const int tid = threadIdx.x;

    // ---- bijective XCD-chunked swizzle (m204) -----------------------------
    const int nwg = gridDim.x;
    const int bid = blockIdx.x;
    const int q = nwg >> 3, r = nwg & 7;
    const int xcd = bid & 7, idx = bid >> 3;
    const int wg = (xcd < r) ? xcd * (q + 1) + idx
                             : r * (q + 1) + (xcd - r) * q + idx;
    const int mtile = wg / KD;
    const int ky = wg - mtile * KD;
    const int m0 = mtile * 64;
    const int kc0 = ky * 3;

    const int lane = tid & 63;
    const int wid = tid >> 6;
    const int wm = wid & 1, wn = wid >> 1;   // 2x2 wave quadrants of 32x64
    const int mrow = lane & 15;
    const int g = lane >> 4;

    const bool anyE = (bid * 256) < E;
    const bool full = (bid * 256 + 256) <= E;   // block-uniform counted path

    // ---- edge loads FIRST (oldest in vmcnt FIFO) --------------------------
    int i0 = 0, ej = 0, ek = 0;
    if (anyE) {
        int e = bid * 256 + tid;
        if (e < E) { i0 = ih[e]; ej = jl[e]; ek = kc[e]; }
    }
    __builtin_amdgcn_sched_barrier(0);

    // ---- stage A (4) + B(kc0) (8) -----------------------------------------
    const ushort* Ag = (const ushort*)Xh + (size_t)m0 * 128;
#pragma unroll
    for (int it = 0; it < 4; ++it) {
        int p = it * 256 + tid;
        int row = p >> 4, cpos = p & 15;
        int csrc = cpos ^ (row & 15);   // XOR swizzle keeps ds_read_b128 conflict-free
        __builtin_amdgcn_global_load_lds(
            (const __attribute__((address_space(1))) void*)(Ag + row * 128 + csrc * 8),
            (__attribute__((address_space(3))) void*)(&sA[row * 128 + cpos * 8]), 16, 0, 0);
    }
    {
        const ushort* Bg = (const ushort*)Wh + (size_t)kc0 * 128 * 128;
#pragma unroll
        for (int it = 0; it < 8; ++it) {
            int p = it * 256 + tid;
            int row = p >> 4, cpos = p & 15;
            int csrc = cpos ^ (row & 15);
            __builtin_amdgcn_global_load_lds(
                (const __attribute__((address_space(1))) void*)(Bg + row * 128 + csrc * 8),
                (__attribute__((address_space(3))) void*)(&sB[row * 128 + cpos * 8]), 16, 0, 0);
        }
    }
    __builtin_amdgcn_sched_barrier(0);

    // ---- epilogue metadata: 3 mask bytes (row=lane) + 3 cidx bases --------
    unsigned char mb0, mb1, mb2; int cb0, cb1, cb2;
    {
        const unsigned char* mp = maskB + (size_t)kc0 * Mpad + m0 + lane;
        mb0 = mp[0]; mb1 = mp[Mpad]; mb2 = mp[2 * Mpad];
        const int* cp = cidx + (size_t)kc0 * Mpad + m0;
        cb0 = cp[0]; cb1 = cp[Mpad]; cb2 = cp[2 * Mpad];
    }
    __builtin_amdgcn_sched_barrier(0);

    // ---- compacted bucket offset + counts atomic --------------------------
    int off0 = 0, pos0 = CAP;
    if (anyE) {
        int e = bid * 256 + tid;
        if (e < E) {
            off0 = cidx[(size_t)ek * Mpad + ej] * 128;   // halfword offset
            pos0 = atomicAdd(&counts[i0], 1);
        }
        __builtin_amdgcn_sched_barrier(0);
        if (full) { asm volatile("s_waitcnt vmcnt(2)" ::: "memory"); }  // cidx_e+atomic fly
        else      { asm volatile("s_waitcnt vmcnt(0)" ::: "memory"); }  // straddler: drain
    } else {
        __builtin_amdgcn_sched_barrier(0);
        asm volatile("s_waitcnt vmcnt(0)" ::: "memory");
    }
    __builtin_amdgcn_sched_barrier(0);
    __builtin_amdgcn_s_barrier();
    __builtin_amdgcn_sched_barrier(0);

#pragma unroll
    for (int kk = 0; kk < 3; ++kk) {
        f32x4 acc[2][4] = {};
#pragma unroll
        for (int kb = 0; kb < 4; ++kb) {
            half8 af[2], bf[4];
            const int cpos8 = ((kb * 4 + g) ^ mrow) * 8;
#pragma unroll
            for (int t = 0; t < 2; ++t) {
                int ra = wm * 32 + t * 16 + mrow;
                af[t] = *reinterpret_cast<const half8*>(&sA[ra * 128 + cpos8]);
            }
#pragma unroll
            for (int t = 0; t < 4; ++t) {
                int rb = wn * 64 + t * 16 + mrow;
                bf[t] = *reinterpret_cast<const half8*>(&sB[rb * 128 + cpos8]);
            }
#pragma unroll
            for (int mt = 0; mt < 2; ++mt)
#pragma unroll
                for (int nt = 0; nt < 4; ++nt)
                    acc[mt][nt] = __builtin_amdgcn_mfma_f32_16x16x32_f16(
                        af[mt], bf[nt], acc[mt][nt], 0, 0, 0);
        }
        if (kk < 2) {
            __builtin_amdgcn_s_barrier();        // all waves done reading sB(kk)
            __builtin_amdgcn_sched_barrier(0);
            if (kk == 0 && anyE) {               // consume BEFORE staging issue:
                int e = bid * 256 + tid;         // its wait drains only cidx_e+atomic
                if (e < E) {
                    if (pos0 < CAP) {
                        bucket[(size_t)i0 * CAP + pos0] = off0;
                    } else {
                        int o = atomicAdd(ovf_cnt, 1);
                        if (o < OVF_MAX) { ovf_list[2 * o] = i0; ovf_list[2 * o + 1] = off0; }
                    }
                }
            }
            __builtin_amdgcn_sched_barrier(0);
            const ushort* Bg = (const ushort*)Wh + (size_t)(kc0 + kk + 1) * 128 * 128;
#pragma unroll
            for (int it = 0; it < 8; ++it) {     // 8 staging loads
                int p = it * 256 + tid;
                int row = p >> 4, cpos = p & 15;
                int csrc = cpos ^ (row & 15);
                __builtin_amdgcn_global_load_lds(
                    (const __attribute__((address_space(1))) void*)(Bg + row * 128 + csrc * 8),
                    (__attribute__((address_space(3))) void*)(&sB[row * 128 + cpos * 8]), 16, 0, 0);
            }
            __builtin_amdgcn_sched_barrier(0);
        }
        // ---- compacted epilogue: ballot + popcll row slots, NT stores -----
        {
            unsigned char mbk = (kk == 0) ? mb0 : (kk == 1) ? mb1 : mb2;  // static
            int cbk = (kk == 0) ? cb0 : (kk == 1) ? cb1 : cb2;
            unsigned long long um = __ballot(mbk != 0);   // bit t = row m0+t used
            const int colOff = wn * 64 + mrow * 4;
#pragma unroll
            for (int mt = 0; mt < 2; ++mt)
#pragma unroll
                for (int rr = 0; rr < 4; ++rr) {
                    int t = wm * 32 + mt * 16 + g * 4 + rr;
                    if ((um >> t) & 1ull) {
                        int crow = cbk + __popcll(um & ((1ull << t) - 1ull));
                        half4v hv;
#pragma unroll
                        for (int nt = 0; nt < 4; ++nt) hv[nt] = (_Float16)acc[mt][nt][rr];
                        __builtin_nontemporal_store(
                            hv, reinterpret_cast<half4v*>(Y + (size_t)crow * 128 + colOff));
                    }
                }
        }
        __builtin_amdgcn_sched_barrier(0);
        if (kk < 2) {
            if (full) { asm volatile("s_waitcnt vmcnt(8)" ::: "memory"); }
            else      { asm volatile("s_waitcnt vmcnt(0)" ::: "memory"); }
            __builtin_amdgcn_sched_barrier(0);
            __builtin_amdgcn_s_barrier();
            __builtin_amdgcn_sched_barrier(0);
        }
        // kk==2: fall through; endpgm drains outstanding stores
    }
}

// ---------------- gather: out[i] = bias + sum_{e in bucket[i]} Y[off_e] -----
__global__ __launch_bounds__(256) void gather_out(
    const _Float16* __restrict__ Y, const int* __restrict__ counts,
    const int* __restrict__ bucket, const float* __restrict__ biasPerm,
    float* __restrict__ out, int Nhigh, int zoff) {
    int wave = (blockIdx.x * blockDim.x + threadIdx.x) >> 6;
    int lane = threadIdx.x & 63;
    int p = lane >> 4;                  // point within wave
    int sub = lane & 15;                // 16B piece within row
    int i = wave * 4 + p;
    bool act = i < Nhigh;
    int iC = act ? i : 0;
    int nb = counts[iC];
    if (nb > CAP) nb = CAP;
    const int* bk = bucket + (size_t)iC * CAP;
    int offsA = bk[sub];                // slots 0..15 across the quarter
    int offsB = bk[sub + 16];           // slots 16..31
    float4 b0 = reinterpret_cast<const float4*>(biasPerm)[sub * 2];
    float4 b1 = reinterpret_cast<const float4*>(biasPerm)[sub * 2 + 1];
    float acc[8] = {b0.x, b0.y, b0.z, b0.w, b1.x, b1.y, b1.z, b1.w};

    int nmax = nb;
    nmax = max(nmax, __shfl_xor(nmax, 16));
    nmax = max(nmax, __shfl_xor(nmax, 32));

    for (int e0 = 0; e0 < nmax; e0 += 8) {
#pragma unroll
        for (int u = 0; u < 8; ++u) {
            int e = e0 + u;                           // wave-uniform
            int off = (e < 16) ? __shfl(offsA, p * 16 + (e & 15))
                               : __shfl(offsB, p * 16 + (e & 15));
            bool valid = act && (e < nb);
            off = valid ? off : zoff;                 // zero row
            half8 h = *reinterpret_cast<const half8*>(Y + (size_t)off + sub * 8);
#pragma unroll
            for (int t = 0; t < 8; ++t) acc[t] += (float)h[t];
        }
    }
    if (act) {
        // channels o = obase+16b and o+1 are t=b and t=b+4 -> 8B stores
        float* op = out + (size_t)i * 128;
        int obase = (sub >> 3) * 64 + (sub & 7) * 2;
#pragma unroll
        for (int b = 0; b < 4; ++b) {
            f32x2 v; v[0] = acc[b]; v[1] = acc[b + 4];
            __builtin_nontemporal_store(
                v, reinterpret_cast<f32x2*>(op + obase + 16 * b));
        }
    }
}

// ---------------- rare overflow application (normally 0 entries) ------------
__global__ void apply_overflow(const int* __restrict__ ovf_cnt, const int* __restrict__ ovf_list,
                               const _Float16* __restrict__ Y, float* __restrict__ out) {
    int n = *ovf_cnt;
    if (n > OVF_MAX) n = OVF_MAX;
    int lane = threadIdx.x & 63;
    int w = threadIdx.x >> 6;        // 4 waves, 1 block
    int o0p = 2 * lane, o1p = 2 * lane + 1;
    int o0 = (o0p >> 6) * 64 + (o0p & 3) * 16 + ((o0p >> 2) & 15);
    int o1 = (o1p >> 6) * 64 + (o1p & 3) * 16 + ((o1p >> 2) & 15);
    for (int o = w; o < n; o += 4) {
        int i = ovf_list[2 * o], off = ovf_list[2 * o + 1];
        half2v h = *reinterpret_cast<const half2v*>(Y + (size_t)off + lane * 2);
        float* dst = out + (size_t)i * 128;
        unsafeAtomicAdd(dst + o0, (float)h[0]);
        unsafeAtomicAdd(dst + o1, (float)h[1]);
    }
}

// ---------------- tier-3 fallback: direct per-edge matvec -------------------
__global__ void fallback_edge(const float* __restrict__ x, const float* __restrict__ w,
                              const int* __restrict__ ih, const int* __restrict__ jl,
                              const int* __restrict__ kc, float* __restrict__ out, int E) {
    int e = blockIdx.x;
    if (e >= E) return;
    int lane = threadIdx.x;   // 64 threads
    int i = ih[e], j = jl[e], k = kc[e];
    const float* xr = x + (size_t)j * 128;
    const float* wk = w + (size_t)k * 128 * 128;
    float s0 = 0.f, s1 = 0.f;
    for (int c = 0; c < 128; ++c) {
        float xv = xr[c];
        s0 += wk[(size_t)lane * 128 + c] * xv;
        s1 += wk[(size_t)(lane + 64) * 128 + c] * xv;
    }
    unsafeAtomicAdd(&out[(size_t)i * 128 + lane], s0);
    unsafeAtomicAdd(&out[(size_t)i * 128 + 64 + lane], s1);
}

extern "C" void kernel_launch(void* const* d_in, const int* in_sizes, int n_in,
                              void* d_out, int out_size, void* d_ws, size_t ws_size,
                              hipStream_t stream) {
    const float* x    = (const float*)d_in[0];
    const float* w    = (const float*)d_in[1];
    const float* bias = (const float*)d_in[2];
    const int*   ih   = (const int*)d_in[3];
    const int*   jl   = (const int*)d_in[4];
    const int*   kc   = (const int*)d_in[5];
    float* out = (float*)d_out;

    const int C = 128;
    const int Nlow = in_sizes[0] / C;
    const int K = in_sizes[1] / (C * C);
    const int E = in_sizes[3];
    const int Nhigh = out_size / C;

    const int mtiles = (Nlow + 63) / 64;      // BM = 64
    const int Mpad = mtiles * 64;
    const int NC = Mpad * K;                  // total cells (div by 4)
    const int nc4 = NC / 4;
    const int nbScan = (nc4 + 1023) / 1024;

    // ---- workspace layout -------------------------------------------------
    size_t off = 0;
    auto alloc = [&](size_t bytes) { size_t o = off; off = (off + bytes + 255) & ~(size_t)255; return o; };
    size_t xh_off   = alloc((size_t)Mpad * C * 2);
    size_t wh_off   = alloc((size_t)K * C * C * 2);
    size_t bp_off   = alloc((size_t)C * 4);                  // permuted bias
    size_t cnt_off  = alloc(((size_t)Nhigh + 1) * 4 + (size_t)NC); // counts+ovf+byte mask
    size_t cix_off  = alloc((size_t)NC * 4);                 // cidx (prefix sum)
    size_t bs_off   = alloc((size_t)nbScan * 4);             // scan block sums
    size_t ovl_off  = alloc((size_t)OVF_MAX * 2 * 4);
    size_t bkt_off  = alloc((size_t)Nhigh * CAP * 4);
    size_t y_off    = alloc(((size_t)NC * C + C) * 2);       // compacted Y + zero row
    size_t need_sort = off;

    _Float16* Xh = (_Float16*)((char*)d_ws + xh_off);
    _Float16* Wh = (_Float16*)((char*)d_ws + wh_off);
    float* biasPerm = (float*)((char*)d_ws + bp_off);
    int* counts  = (int*)((char*)d_ws + cnt_off);
    int* ovf_cnt = counts + Nhigh;
    unsigned char* maskB = (unsigned char*)(counts + Nhigh + 1);
    int* cidx    = (int*)((char*)d_ws + cix_off);
    int* bsums   = (int*)((char*)d_ws + bs_off);
    int* ovf_lst = (int*)((char*)d_ws + ovl_off);
    int* bucket  = (int*)((char*)d_ws + bkt_off);
    _Float16* Y  = (_Float16*)((char*)d_ws + y_off);
    const int zoff = NC * C;                                 // zero-row offset (halfwords)

    int KD = K / 3;
    int nwg = mtiles * KD;
    bool edgesFit = (long long)E <= (long long)nwg * 256;

    if (ws_size >= need_sort && (K % 3) == 0 && edgesFit) {
        int xv4 = Nlow * C / 4, xt4 = Mpad * C / 4;
        int w4 = K * C * C / 4;

        // counts + ovf + byte mask are contiguous -> one async memset
        size_t nzb = ((size_t)Nhigh + 1) * 4 + (size_t)NC;
        hipMemsetAsync(counts, 0, nzb, stream);

        int totalCvt = xt4 + w4 + 48 + E;
        cvt_mask<<<(totalCvt + 255) / 256, 256, 0, stream>>>(
            x, w, bias, Xh, Wh, biasPerm, Y + (size_t)zoff,
            jl, kc, maskB, Mpad, xv4, xt4, w4, E);

        scan_sums<<<nbScan, 256, 0, stream>>>((const unsigned*)maskB, nc4, bsums);
        scan_write<<<nbScan, 256, 0, stream>>>((const unsigned*)maskB, nc4, bsums, cidx);

        gemm_xw<<<nwg, 256, 0, stream>>>(
            Xh, Wh, Y, maskB, cidx, Mpad, KD,
            ih, jl, kc, counts, bucket, ovf_cnt, ovf_lst, E);

        gather_out<<<(Nhigh + 15) / 16, 256, 0, stream>>>(
            Y, counts, bucket, biasPerm, out, Nhigh, zoff);
        apply_overflow<<<1, 256, 0, stream>>>(ovf_cnt, ovf_lst, Y, out);
    } else {
        int n4out = out_size / 4;
        init_bias<<<(n4out + 255) / 256, 256, 0, stream>>>(out, bias, n4out);
        fallback_edge<<<E, 64, 0, stream>>>(x, w, ih, jl, kc, out, E);
    }
}

// Round 12
// 321.889 us; speedup vs baseline: 1.0908x; 1.0908x over previous
//
#include <hip/hip_runtime.h>

typedef _Float16 half8 __attribute__((ext_vector_type(8)));
typedef _Float16 half4v __attribute__((ext_vector_type(4)));
typedef _Float16 half2v __attribute__((ext_vector_type(2)));
typedef float f32x4 __attribute__((ext_vector_type(4)));
typedef float f32x2 __attribute__((ext_vector_type(2)));

#define CAP 32          // bucket capacity per output point (mean load = 5)
#define OVF_MAX 4096

// R12 = R9 (best verified: 323 us) + overflow folded into gather + unroll-12.
// Y layout: [K][Mpad][128] dense planes, NT stores. Row-internal permutation:
// position o' holds output channel o = (o'>>6)*64 + (o'&3)*16 + ((o'>>2)&15)

// ---------------- out[i][o] = bias[o] (fallback path only) ------------------
__global__ void init_bias(float* __restrict__ out, const float* __restrict__ bias, int n4) {
    int i = blockIdx.x * blockDim.x + threadIdx.x;
    if (i >= n4) return;
    reinterpret_cast<float4*>(out)[i] = reinterpret_cast<const float4*>(bias)[i & 31];
}

// ---------------- fused: fp32->fp16 cvt + bias perm + Y zero row +
//                  used-cell byte-mask + remainder bucket-fill ---------------
__global__ __launch_bounds__(256) void cvt_mask(
    const float* __restrict__ x, const float* __restrict__ w,
    const float* __restrict__ bias,
    _Float16* __restrict__ Xh, _Float16* __restrict__ Wh,
    float* __restrict__ biasPerm, _Float16* __restrict__ Yz,
    const int* __restrict__ ih, const int* __restrict__ jl,
    const int* __restrict__ kc,
    unsigned char* __restrict__ maskB,
    int* __restrict__ counts, int* __restrict__ bucket,
    int* __restrict__ ovf_cnt, int* __restrict__ ovf_list,
    int Mpad, int xv4, int xt4, int w4, int E, int eg) {
    int i = blockIdx.x * blockDim.x + threadIdx.x;
    if (i < xt4) {
        float4 v = (i < xv4) ? reinterpret_cast<const float4*>(x)[i]
                             : make_float4(0.f, 0.f, 0.f, 0.f);
        half4v h; h[0]=(_Float16)v.x; h[1]=(_Float16)v.y; h[2]=(_Float16)v.z; h[3]=(_Float16)v.w;
        reinterpret_cast<half4v*>(Xh)[i] = h;
    } else if (i < xt4 + w4) {
        int j = i - xt4;
        float4 v = reinterpret_cast<const float4*>(w)[j];
        half4v h; h[0]=(_Float16)v.x; h[1]=(_Float16)v.y; h[2]=(_Float16)v.z; h[3]=(_Float16)v.w;
        reinterpret_cast<half4v*>(Wh)[j] = h;
    } else if (i < xt4 + w4 + 32) {
        int j2 = i - xt4 - w4;           // float4 index into biasPerm (o'=4*j2)
        int wn = j2 >> 4, mrow = j2 & 15;
        float4 v;
        v.x = bias[wn * 64 + 0 * 16 + mrow];
        v.y = bias[wn * 64 + 1 * 16 + mrow];
        v.z = bias[wn * 64 + 2 * 16 + mrow];
        v.w = bias[wn * 64 + 3 * 16 + mrow];
        reinterpret_cast<float4*>(biasPerm)[j2] = v;
    } else if (i < xt4 + w4 + 48) {
        int t = i - xt4 - w4 - 32;       // Y zero row: 16 x int4 = 256 B
        reinterpret_cast<int4*>(Yz)[t] = make_int4(0, 0, 0, 0);
    } else {
        int e = i - (xt4 + w4 + 48);
        if (e < E) {
            int j = jl[e], kk = kc[e];
            maskB[(size_t)kk * Mpad + j] = 1;
            if (e >= eg) {               // remainder bucket-fill
                int ii = ih[e];
                int off = (kk * Mpad + j) * 128;   // [K][Mpad][128] row offset
                int pos = atomicAdd(&counts[ii], 1);
                if (pos < CAP) {
                    bucket[(size_t)ii * CAP + pos] = off;
                } else {
                    int o = atomicAdd(ovf_cnt, 1);
                    if (o < OVF_MAX) { ovf_list[2 * o] = ii; ovf_list[2 * o + 1] = off; }
                }
            }
        }
    }
}

// ---------------- GEMM: Y[kcell][m] = X[m,:] * W[kcell]^T -------------------
// R9-verified BM=64 schedule (3 blocks/CU, 12 waves/CU): A+B staged via
// global_load_lds, counted vmcnt waits (never 0 mid-loop), raw barriers,
// bucket atomic hidden in the prologue, masked branchy NT epilogue,
// XCD-chunked bijective swizzle. Byte-identical to R9's gemm.
__global__ __launch_bounds__(256, 3) void gemm_xw(
    const _Float16* __restrict__ Xh,   // [Mpad][128]
    const _Float16* __restrict__ Wh,   // [K][128][128]  (o-major, c contiguous)
    _Float16* __restrict__ Y,          // [K][Mpad][128] (permuted rows)
    const unsigned char* __restrict__ maskB, // used-cell bytes, idx = kcell*Mpad+m
    int Mpad, int KD,                  // KD = K/3 (y-blocks per m-tile)
    const int* __restrict__ ih, const int* __restrict__ jl,
    const int* __restrict__ kc,
    int* __restrict__ counts, int* __restrict__ bucket,
    int* __restrict__ ovf_cnt, int* __restrict__ ovf_list, int eg) {
    __shared__ ushort sA[64 * 128];    // 16 KB
    __shared__ ushort sB[128 * 128];   // 32 KB
    const int tid = threadIdx.x;

    // ---- bijective XCD-chunked swizzle (m204) -----------------------------
    const int nwg = gridDim.x;
    const int bid = blockIdx.x;
    const int q = nwg >> 3, r = nwg & 7;
    const int xcd = bid & 7, idx = bid >> 3;
    const int wg = (xcd < r) ? xcd * (q + 1) + idx
                             : r * (q + 1) + (xcd - r) * q + idx;
    const int mtile = wg / KD;
    const int ky = wg - mtile * KD;
    const int m0 = mtile * 64;
    const int kc0 = ky * 3;

    // ---- stage A (4 iters) + B(kc0) (8 iters) -----------------------------
    const ushort* Ag = (const ushort*)Xh + (size_t)m0 * 128;
#pragma unroll
    for (int it = 0; it < 4; ++it) {
        int p = it * 256 + tid;
        int row = p >> 4, cpos = p & 15;
        int csrc = cpos ^ (row & 15);   // XOR swizzle keeps ds_read_b128 conflict-free
        __builtin_amdgcn_global_load_lds(
            (const __attribute__((address_space(1))) void*)(Ag + row * 128 + csrc * 8),
            (__attribute__((address_space(3))) void*)(&sA[row * 128 + cpos * 8]), 16, 0, 0);
    }
    {
        const ushort* Bg = (const ushort*)Wh + (size_t)kc0 * 128 * 128;
#pragma unroll
        for (int it = 0; it < 8; ++it) {
            int p = it * 256 + tid;
            int row = p >> 4, cpos = p & 15;
            int csrc = cpos ^ (row & 15);
            __builtin_amdgcn_global_load_lds(
                (const __attribute__((address_space(1))) void*)(Bg + row * 128 + csrc * 8),
                (__attribute__((address_space(3))) void*)(&sB[row * 128 + cpos * 8]), 16, 0, 0);
        }
    }
    __builtin_amdgcn_sched_barrier(0);   // pin: all 12 staging ops issued above

    // ---- bucket-fill issue: 3 loads + 1 atomic per thread (uniform) -------
    const bool hasE = (bid * 256) < eg;  // eg multiple of 256 -> block-uniform
    int i0 = 0, off0 = 0, pos0 = CAP;
    if (hasE) {
        int e = bid * 256 + tid;
        i0 = ih[e];
        off0 = (kc[e] * Mpad + jl[e]) * 128;
        pos0 = atomicAdd(&counts[i0], 1);
        __builtin_amdgcn_sched_barrier(0);
        asm volatile("s_waitcnt vmcnt(4)" ::: "memory");   // staging done; atomic in flight
    } else {
        __builtin_amdgcn_sched_barrier(0);
        asm volatile("s_waitcnt vmcnt(0)" ::: "memory");
    }
    __builtin_amdgcn_sched_barrier(0);
    __builtin_amdgcn_s_barrier();        // raw: no vmcnt(0) drain of the atomic
    __builtin_amdgcn_sched_barrier(0);

    const int lane = tid & 63;
    const int wid = tid >> 6;
    const int wm = wid & 1, wn = wid >> 1;   // 2x2 wave quadrants of 32x64
    const int mrow = lane & 15;
    const int g = lane >> 4;

    for (int kk = 0; kk < 3; ++kk) {
        f32x4 acc[2][4] = {};
#pragma unroll
        for (int kb = 0; kb < 4; ++kb) {
            half8 af[2], bf[4];
            const int cpos8 = ((kb * 4 + g) ^ mrow) * 8;
#pragma unroll
            for (int t = 0; t < 2; ++t) {
                int ra = wm * 32 + t * 16 + mrow;
                af[t] = *reinterpret_cast<const half8*>(&sA[ra * 128 + cpos8]);
            }
#pragma unroll
            for (int t = 0; t < 4; ++t) {
                int rb = wn * 64 + t * 16 + mrow;
                bf[t] = *reinterpret_cast<const half8*>(&sB[rb * 128 + cpos8]);
            }
#pragma unroll
            for (int mt = 0; mt < 2; ++mt)
#pragma unroll
                for (int nt = 0; nt < 4; ++nt)
                    acc[mt][nt] = __builtin_amdgcn_mfma_f32_16x16x32_f16(
                        af[mt], bf[nt], acc[mt][nt], 0, 0, 0);
        }
        if (kk < 2) {
            // raw barrier: compiler's lgkmcnt waits before the MFMAs above
            // guarantee every wave's sB ds_reads retired; no vmcnt drain needed.
            __builtin_amdgcn_s_barrier();
            __builtin_amdgcn_sched_barrier(0);
            const ushort* Bg = (const ushort*)Wh + (size_t)(kc0 + kk + 1) * 128 * 128;
#pragma unroll
            for (int it = 0; it < 8; ++it) {     // 8 staging loads (oldest)
                int p = it * 256 + tid;
                int row = p >> 4, cpos = p & 15;
                int csrc = cpos ^ (row & 15);
                __builtin_amdgcn_global_load_lds(
                    (const __attribute__((address_space(1))) void*)(Bg + row * 128 + csrc * 8),
                    (__attribute__((address_space(3))) void*)(&sB[row * 128 + cpos * 8]), 16, 0, 0);
            }
            __builtin_amdgcn_sched_barrier(0);
        }
        if (kk == 0 && hasE) {                   // consume atomic result
            if (pos0 < CAP) {
                bucket[(size_t)i0 * CAP + pos0] = off0;
            } else {
                int o = atomicAdd(ovf_cnt, 1);
                if (o < OVF_MAX) { ovf_list[2 * o] = i0; ovf_list[2 * o + 1] = off0; }
            }
        }
        // ---- epilogue: masked 8B NT stores; per (mt,r) 16 lanes = 128B ----
        const unsigned char* mBp = maskB + (size_t)(kc0 + kk) * Mpad + m0 + wm * 32;
        _Float16* Yt = Y + ((size_t)(kc0 + kk) * Mpad + m0) * 128 + wn * 64 + mrow * 4;
#pragma unroll
        for (int mt = 0; mt < 2; ++mt) {
            unsigned mw = *reinterpret_cast<const unsigned*>(mBp + mt * 16 + g * 4);
            if (mw) {
#pragma unroll
                for (int r = 0; r < 4; ++r) {
                    if ((mw >> (8 * r)) & 0xFFu) {
                        int row = wm * 32 + mt * 16 + g * 4 + r;
                        half4v hv;
#pragma unroll
                        for (int nt = 0; nt < 4; ++nt) hv[nt] = (_Float16)acc[mt][nt][r];
                        __builtin_nontemporal_store(
                            hv, reinterpret_cast<half4v*>(Yt + (size_t)row * 128));
                    }
                }
            }
        }
        __builtin_amdgcn_sched_barrier(0);
        if (kk == 0) {
            if (hasE) { asm volatile("s_waitcnt vmcnt(9)" ::: "memory"); }
            else      { asm volatile("s_waitcnt vmcnt(8)" ::: "memory"); }
            __builtin_amdgcn_sched_barrier(0);
            __builtin_amdgcn_s_barrier();
            __builtin_amdgcn_sched_barrier(0);
        } else if (kk == 1) {
            asm volatile("s_waitcnt vmcnt(8)" ::: "memory");
            __builtin_amdgcn_sched_barrier(0);
            __builtin_amdgcn_s_barrier();
            __builtin_amdgcn_sched_barrier(0);
        }
        // kk==2: fall through; endpgm drains outstanding stores
    }
}

// ---------------- gather: out[i] = bias + sum_{e in bucket[i]} Y[off_e] -----
// 4 points per wave, 16 lanes x half8 per row; unroll-12 keeps 12 row loads
// in flight (mean wave-max count ~9.3 -> usually ONE outer round vs two at
// unroll-8; padding rounds hit the L1-cached zero row).
// Overflow (counts[i] > CAP, normally never) handled inline for this wave's
// own points -- no ordering race, and the apply_overflow launch is gone.
__global__ __launch_bounds__(256) void gather_out(
    const _Float16* __restrict__ Y, const int* __restrict__ counts,
    const int* __restrict__ bucket, const float* __restrict__ biasPerm,
    float* __restrict__ out, int Nhigh, int zoff,
    const int* __restrict__ ovf_cnt, const int* __restrict__ ovf_list) {
    int wave = (blockIdx.x * blockDim.x + threadIdx.x) >> 6;
    int lane = threadIdx.x & 63;
    int p = lane >> 4;                  // point within wave
    int sub = lane & 15;                // 16B piece within row
    int i = wave * 4 + p;
    bool act = i < Nhigh;
    int iC = act ? i : 0;
    int nbr = counts[iC];               // raw count (may exceed CAP)
    int nb = (nbr > CAP) ? CAP : nbr;
    const int* bk = bucket + (size_t)iC * CAP;
    int offsA = bk[sub];                // slots 0..15 across the quarter
    int offsB = bk[sub + 16];           // slots 16..31
    float4 b0 = reinterpret_cast<const float4*>(biasPerm)[sub * 2];
    float4 b1 = reinterpret_cast<const float4*>(biasPerm)[sub * 2 + 1];
    float acc[8] = {b0.x, b0.y, b0.z, b0.w, b1.x, b1.y, b1.z, b1.w};

    int nmax = nb;
    nmax = max(nmax, __shfl_xor(nmax, 16));
    nmax = max(nmax, __shfl_xor(nmax, 32));

    for (int e0 = 0; e0 < nmax; e0 += 12) {
#pragma unroll
        for (int u = 0; u < 12; ++u) {
            int e = e0 + u;                           // wave-uniform
            int off = (e < 16) ? __shfl(offsA, p * 16 + (e & 15))
                               : __shfl(offsB, p * 16 + (e & 15));
            bool valid = act && (e < nb);
            off = valid ? off : zoff;                 // zero row
            half8 h = *reinterpret_cast<const half8*>(Y + (size_t)off + sub * 8);
#pragma unroll
            for (int t = 0; t < 8; ++t) acc[t] += (float)h[t];
        }
    }
    // ---- rare overflow path: this wave's own points only (race-free) ------
    if (__any(act && nbr > CAP)) {
        int n = *ovf_cnt;
        if (n > OVF_MAX) n = OVF_MAX;
        for (int o = 0; o < n; ++o) {
            int oi = ovf_list[2 * o];
            int off = ovf_list[2 * o + 1];
            if (act && nbr > CAP && oi == i) {
                half8 h = *reinterpret_cast<const half8*>(Y + (size_t)off + sub * 8);
#pragma unroll
                for (int t = 0; t < 8; ++t) acc[t] += (float)h[t];
            }
        }
    }
    if (act) {
        // channels o = obase+16b and o+1 are t=b and t=b+4 -> 8B stores
        float* op = out + (size_t)i * 128;
        int obase = (sub >> 3) * 64 + (sub & 7) * 2;
#pragma unroll
        for (int b = 0; b < 4; ++b) {
            f32x2 v; v[0] = acc[b]; v[1] = acc[b + 4];
            __builtin_nontemporal_store(
                v, reinterpret_cast<f32x2*>(op + obase + 16 * b));
        }
    }
}

// ---------------- tier-3 fallback: direct per-edge matvec -------------------
__global__ void fallback_edge(const float* __restrict__ x, const float* __restrict__ w,
                              const int* __restrict__ ih, const int* __restrict__ jl,
                              const int* __restrict__ kc, float* __restrict__ out, int E) {
    int e = blockIdx.x;
    if (e >= E) return;
    int lane = threadIdx.x;   // 64 threads
    int i = ih[e], j = jl[e], k = kc[e];
    const float* xr = x + (size_t)j * 128;
    const float* wk = w + (size_t)k * 128 * 128;
    float s0 = 0.f, s1 = 0.f;
    for (int c = 0; c < 128; ++c) {
        float xv = xr[c];
        s0 += wk[(size_t)lane * 128 + c] * xv;
        s1 += wk[(size_t)(lane + 64) * 128 + c] * xv;
    }
    unsafeAtomicAdd(&out[(size_t)i * 128 + lane], s0);
    unsafeAtomicAdd(&out[(size_t)i * 128 + 64 + lane], s1);
}

extern "C" void kernel_launch(void* const* d_in, const int* in_sizes, int n_in,
                              void* d_out, int out_size, void* d_ws, size_t ws_size,
                              hipStream_t stream) {
    const float* x    = (const float*)d_in[0];
    const float* w    = (const float*)d_in[1];
    const float* bias = (const float*)d_in[2];
    const int*   ih   = (const int*)d_in[3];
    const int*   jl   = (const int*)d_in[4];
    const int*   kc   = (const int*)d_in[5];
    float* out = (float*)d_out;

    const int C = 128;
    const int Nlow = in_sizes[0] / C;
    const int K = in_sizes[1] / (C * C);
    const int E = in_sizes[3];
    const int Nhigh = out_size / C;

    const int mtiles = (Nlow + 63) / 64;      // BM = 64
    const int Mpad = mtiles * 64;

    // ---- workspace layout -------------------------------------------------
    size_t off = 0;
    auto alloc = [&](size_t bytes) { size_t o = off; off = (off + bytes + 255) & ~(size_t)255; return o; };
    size_t xh_off   = alloc((size_t)Mpad * C * 2);
    size_t wh_off   = alloc((size_t)K * C * C * 2);
    size_t bp_off   = alloc((size_t)C * 4);                  // permuted bias
    size_t cnt_off  = alloc(((size_t)Nhigh + 1) * 4 + (size_t)Mpad * K); // counts+ovf+byte mask
    size_t ovl_off  = alloc((size_t)OVF_MAX * 2 * 4);
    size_t bkt_off  = alloc((size_t)Nhigh * CAP * 4);
    size_t y_off    = alloc(((size_t)K * Mpad * C + C) * 2); // [K][Mpad][128] + zero row
    size_t need_sort = off;

    _Float16* Xh = (_Float16*)((char*)d_ws + xh_off);
    _Float16* Wh = (_Float16*)((char*)d_ws + wh_off);
    float* biasPerm = (float*)((char*)d_ws + bp_off);
    int* counts  = (int*)((char*)d_ws + cnt_off);
    int* ovf_cnt = counts + Nhigh;
    unsigned char* maskB = (unsigned char*)(counts + Nhigh + 1);
    int* ovf_lst = (int*)((char*)d_ws + ovl_off);
    int* bucket  = (int*)((char*)d_ws + bkt_off);
    _Float16* Y  = (_Float16*)((char*)d_ws + y_off);
    const int zoff = K * Mpad * C;                           // zero-row offset (halfwords)

    if (ws_size >= need_sort && (K % 3) == 0) {
        int xv4 = Nlow * C / 4, xt4 = Mpad * C / 4;
        int w4 = K * C * C / 4;
        int KD = K / 3;
        int nwg = mtiles * KD;
        long long cap256 = (long long)nwg * 256;
        int eg = (E < cap256) ? (E & ~255) : (int)cap256;   // gemm-handled edges [0,eg)

        // counts + ovf + byte mask are contiguous -> one async memset
        size_t nzb = ((size_t)Nhigh + 1) * 4 + (size_t)Mpad * K;
        hipMemsetAsync(counts, 0, nzb, stream);

        int totalCvt = xt4 + w4 + 48 + E;
        cvt_mask<<<(totalCvt + 255) / 256, 256, 0, stream>>>(
            x, w, bias, Xh, Wh, biasPerm, Y + (size_t)zoff,
            ih, jl, kc, maskB, counts, bucket, ovf_cnt, ovf_lst,
            Mpad, xv4, xt4, w4, E, eg);

        gemm_xw<<<nwg, 256, 0, stream>>>(
            Xh, Wh, Y, maskB, Mpad, KD,
            ih, jl, kc, counts, bucket, ovf_cnt, ovf_lst, eg);

        gather_out<<<(Nhigh + 15) / 16, 256, 0, stream>>>(
            Y, counts, bucket, biasPerm, out, Nhigh, zoff, ovf_cnt, ovf_lst);
    } else {
        int n4out = out_size / 4;
        init_bias<<<(n4out + 255) / 256, 256, 0, stream>>>(out, bias, n4out);
        fallback_edge<<<E, 64, 0, stream>>>(x, w, ih, jl, kc, out, E);
    }
}